// Round 1
// baseline (2591.047 us; speedup 1.0000x reference)
//
#include <hip/hip_runtime.h>

#define N_NODES  100000
#define N_EDGES  3200000
#define N_GRAPHS 3200

// ---------------- utility kernels ----------------

__global__ void zero_int_kernel(int* __restrict__ p, int n) {
    int i = blockIdx.x * blockDim.x + threadIdx.x;
    if (i < n) p[i] = 0;
}

__global__ void deg_count_kernel(const int* __restrict__ dst, int* __restrict__ deg, int E) {
    int e = blockIdx.x * blockDim.x + threadIdx.x;
    if (e < E) atomicAdd(&deg[dst[e]], 1);
}

// single-block scan: offsets[i] = exclusive prefix of deg, offsets[n] = total; cursor = copy
__global__ void scan_offsets_kernel(const int* __restrict__ deg, int* __restrict__ offsets,
                                    int* __restrict__ cursor, int n) {
    __shared__ int part[256];
    int t = threadIdx.x;
    int chunk = (n + 255) / 256;
    int lo = t * chunk; if (lo > n) lo = n;
    int hi = lo + chunk; if (hi > n) hi = n;
    int s = 0;
    for (int i = lo; i < hi; ++i) s += deg[i];
    part[t] = s;
    __syncthreads();
    for (int off = 1; off < 256; off <<= 1) {
        int v = part[t];
        int add = (t >= off) ? part[t - off] : 0;
        __syncthreads();
        part[t] = v + add;
        __syncthreads();
    }
    int run = (t == 0) ? 0 : part[t - 1];
    for (int i = lo; i < hi; ++i) {
        offsets[i] = run;
        cursor[i]  = run;
        run += deg[i];
    }
    if (t == 255) offsets[n] = run;
}

__global__ void fill_csr_kernel(const int* __restrict__ src, const int* __restrict__ dst,
                                int* __restrict__ cursor, int* __restrict__ csr_src, int E) {
    int e = blockIdx.x * blockDim.x + threadIdx.x;
    if (e < E) {
        int d = dst[e];
        int pos = atomicAdd(&cursor[d], 1);
        csr_src[pos] = src[e];
    }
}

__global__ void compute_dis_kernel(const int* __restrict__ deg, float* __restrict__ dis, int n) {
    int i = blockIdx.x * blockDim.x + threadIdx.x;
    if (i < n) dis[i] = rsqrtf((float)deg[i] + 1.0f);
}

// ---------------- GEMM: out[m][c] = (sum_k H[m][k]*W[k][c]) * (SCALE? dis[m]:1) + (BIAS? bias[c]:0)
// block = N threads, R rows per block; H rows staged in LDS (contiguous flat copy).
template<int K, int N, int R, bool SCALE, bool BIAS>
__global__ void gemm_kernel(const float* __restrict__ H, const float* __restrict__ W,
                            const float* __restrict__ dis, const float* __restrict__ bias,
                            float* __restrict__ out, int M) {
    __shared__ float lds[R * K];
    int row0 = blockIdx.x * R;
    int t = threadIdx.x;
    const float* src = H + (size_t)row0 * K;
    int limit = R * K;
    int rows_here = M - row0; if (rows_here > R) rows_here = R;
    limit = rows_here * K;
    for (int i = t; i < limit; i += N) lds[i] = src[i];
    __syncthreads();
    float acc[R];
#pragma unroll
    for (int r = 0; r < R; ++r) acc[r] = 0.0f;
#pragma unroll 4
    for (int k = 0; k < K; ++k) {
        float wv = W[(size_t)k * N + t];
#pragma unroll
        for (int r = 0; r < R; ++r) acc[r] += lds[r * K + k] * wv;
    }
#pragma unroll
    for (int r = 0; r < R; ++r) {
        int row = row0 + r;
        if (row < M) {
            float v = acc[r];
            if (SCALE) v *= dis[row];
            if (BIAS)  v += bias[t];
            out[(size_t)row * N + t] = v;
        }
    }
}

// ---------------- aggregation: out[n][f] = relu(dis[n]*(hWd[n][f] + sum_{in-edges} hWd[src][f]) + b[f])
template<int F>
__global__ void agg_kernel(const float* __restrict__ hWd, const int* __restrict__ csr_src,
                           const int* __restrict__ offsets, const float* __restrict__ dis,
                           const float* __restrict__ bias, float* __restrict__ out) {
    int n = blockIdx.x;
    int t = threadIdx.x;
    float acc = hWd[(size_t)n * F + t];
    int lo = offsets[n], hi = offsets[n + 1];
    for (int j = lo; j < hi; ++j) {
        int s = csr_src[j];
        acc += hWd[(size_t)s * F + t];
    }
    float v = dis[n] * acc + bias[t];
    out[(size_t)n * F + t] = fmaxf(v, 0.0f);
}

// ---------------- pooling: batch is sorted; per-graph segment via binary search
__device__ __forceinline__ int lower_bound_dev(const int* __restrict__ a, int n, int key) {
    int lo = 0, hi = n;
    while (lo < hi) {
        int mid = (lo + hi) >> 1;
        if (a[mid] < key) lo = mid + 1; else hi = mid;
    }
    return lo;
}

__global__ void pool_kernel(const float* __restrict__ h, const int* __restrict__ batch,
                            float* __restrict__ pooled, int nNodes) {
    int g = blockIdx.x;
    int t = threadIdx.x; // 0..255
    __shared__ int bounds[2];
    if (t == 0) bounds[0] = lower_bound_dev(batch, nNodes, g);
    if (t == 1) bounds[1] = lower_bound_dev(batch, nNodes, g + 1);
    __syncthreads();
    int lo = bounds[0], hi = bounds[1];
    float acc = 0.0f;
    for (int n = lo; n < hi; ++n) acc += h[(size_t)n * 256 + t];
    float cnt = (float)(hi - lo);
    pooled[(size_t)g * 256 + t] = acc / fmaxf(cnt, 1.0f);
}

// ---------------- launch ----------------

static inline size_t align_up(size_t x, size_t a) { return (x + a - 1) & ~(a - 1); }

extern "C" void kernel_launch(void* const* d_in, const int* in_sizes, int n_in,
                              void* d_out, int out_size, void* d_ws, size_t ws_size,
                              hipStream_t stream) {
    const float* x  = (const float*)d_in[0];
    const float* W1 = (const float*)d_in[1];
    const float* b1 = (const float*)d_in[2];
    const float* W2 = (const float*)d_in[3];
    const float* b2 = (const float*)d_in[4];
    const float* W3 = (const float*)d_in[5];
    const float* b3 = (const float*)d_in[6];
    const float* Wp = (const float*)d_in[7];
    const float* bp = (const float*)d_in[8];
    const int*   ei = (const int*)d_in[9];   // [2, E]
    const int*   batch = (const int*)d_in[10];
    float* out = (float*)d_out;

    const int* e_src = ei;
    const int* e_dst = ei + N_EDGES;

    // workspace layout
    char* p = (char*)d_ws;
    size_t off = 0;
    auto take = [&](size_t bytes) {
        void* r = p + off;
        off = align_up(off + bytes, 256);
        return r;
    };
    int*   deg     = (int*)  take(sizeof(int) * N_NODES);
    int*   offsets = (int*)  take(sizeof(int) * (N_NODES + 1));
    int*   cursor  = (int*)  take(sizeof(int) * N_NODES);
    int*   csr_src = (int*)  take(sizeof(int) * N_EDGES);
    float* dis     = (float*)take(sizeof(float) * N_NODES);
    float* pooled  = (float*)take(sizeof(float) * N_GRAPHS * 256);
    float* bufA    = (float*)take(sizeof(float) * (size_t)N_NODES * 256); // hWd
    float* bufB    = (float*)take(sizeof(float) * (size_t)N_NODES * 256); // h

    const int TB = 256;
    int nodeBlocks = (N_NODES + TB - 1) / TB;
    int edgeBlocks = (N_EDGES + TB - 1) / TB;

    // CSR build
    zero_int_kernel<<<nodeBlocks, TB, 0, stream>>>(deg, N_NODES);
    deg_count_kernel<<<edgeBlocks, TB, 0, stream>>>(e_dst, deg, N_EDGES);
    scan_offsets_kernel<<<1, 256, 0, stream>>>(deg, offsets, cursor, N_NODES);
    fill_csr_kernel<<<edgeBlocks, TB, 0, stream>>>(e_src, e_dst, cursor, csr_src, N_EDGES);
    compute_dis_kernel<<<nodeBlocks, TB, 0, stream>>>(deg, dis, N_NODES);

    // Layer 1: 37 -> 128
    gemm_kernel<37, 128, 16, true, false><<<N_NODES / 16, 128, 0, stream>>>(x, W1, dis, nullptr, bufA, N_NODES);
    agg_kernel<128><<<N_NODES, 128, 0, stream>>>(bufA, csr_src, offsets, dis, b1, bufB);

    // Layer 2: 128 -> 256
    gemm_kernel<128, 256, 16, true, false><<<N_NODES / 16, 256, 0, stream>>>(bufB, W2, dis, nullptr, bufA, N_NODES);
    agg_kernel<256><<<N_NODES, 256, 0, stream>>>(bufA, csr_src, offsets, dis, b2, bufB);

    // Layer 3: 256 -> 256
    gemm_kernel<256, 256, 16, true, false><<<N_NODES / 16, 256, 0, stream>>>(bufB, W3, dis, nullptr, bufA, N_NODES);
    agg_kernel<256><<<N_NODES, 256, 0, stream>>>(bufA, csr_src, offsets, dis, b3, bufB);

    // global mean pool
    pool_kernel<<<N_GRAPHS, 256, 0, stream>>>(bufB, batch, pooled, N_NODES);

    // head: pooled @ Wp + bp
    gemm_kernel<256, 256, 16, false, true><<<N_GRAPHS / 16, 256, 0, stream>>>(pooled, Wp, nullptr, bp, out, N_GRAPHS);
}